// Round 1
// baseline (602.476 us; speedup 1.0000x reference)
//
#include <hip/hip_runtime.h>
#include <hip/hip_bf16.h>
#include <math.h>

// Problem constants (from reference setup_inputs)
#define SS 200
#define BB 1024
#define DD 128
#define FF 512
#define LL1 80
#define LL2 40
#define PP (SS*BB)            // 204800 flattened (s,b) pairs
#define MASK_FILL_F (-4294967295.0f)

// ---------------------------------------------------------------------------
// K0: detect mask storage layout. int32 0/1 values have bytes 1,2,3 of each
// word == 0; bool (1-byte) layout has ~50% nonzero at every byte position.
__global__ void k_detect_mask(const unsigned char* __restrict__ mask, int* __restrict__ flag) {
    if (threadIdx.x == 0 && blockIdx.x == 0) {
        int f = 0;
        for (int i = 0; i < 256; ++i)
            if ((i & 3) && mask[i]) f = 1;   // nonzero at non-word-aligned byte => bool layout
        *flag = f;
    }
}

// ---------------------------------------------------------------------------
// K1: z1[p][l] = sum_d q[qr(p)][d]*(Wa+Wd)[d][l] + f[p][d]*(Wb-Wd)[d][l]
//                     + q*f*(Wc)[d][l]        (+ b1 later)
// where qr(p) = p / S  (the tile+reshape permutation resolved).
// Block: 256 threads, 128 pairs. Thread: 4 pairs x 10 l outputs.
__global__ __launch_bounds__(256) void k1_gemm1(
    const float* __restrict__ query, const float* __restrict__ facts,
    const float* __restrict__ W1, const float* __restrict__ b1,
    float* __restrict__ z1) {
    const int tid = threadIdx.x;
    const int p0  = blockIdx.x * 128;
    const int pg  = tid >> 3;       // 0..31  -> pair group (4 pairs)
    const int lg  = tid & 7;        // 0..7   -> l group (10 l's)
    const int l0  = lg * 10;

    __shared__ float wq[32 * LL1];
    __shared__ float wf[32 * LL1];
    __shared__ float wc[32 * LL1];

    float acc[40];
#pragma unroll
    for (int i = 0; i < 40; ++i) acc[i] = 0.f;

    int pr[4], qr[4];
#pragma unroll
    for (int j = 0; j < 4; ++j) {
        pr[j] = p0 + pg * 4 + j;
        qr[j] = pr[j] / SS;
    }

    for (int d0 = 0; d0 < DD; d0 += 32) {
        __syncthreads();
        // stage + fold weights for this d-chunk
        for (int e = tid; e < 32 * LL1; e += 256) {
            int d = e / LL1;
            int l = e - d * LL1;
            int fi = (d0 + d) * LL1 + l;
            float wa = W1[fi];
            float wb = W1[fi + 128 * LL1];
            float wv = W1[fi + 256 * LL1];
            float wd = W1[fi + 384 * LL1];
            wq[e] = wa + wd;
            wf[e] = wb - wd;
            wc[e] = wv;
        }
        __syncthreads();

        for (int dd = 0; dd < 32; dd += 4) {
            float4 q4[4], f4[4];
#pragma unroll
            for (int j = 0; j < 4; ++j) {
                q4[j] = *(const float4*)&query[qr[j] * DD + d0 + dd];
                f4[j] = *(const float4*)&facts[pr[j] * DD + d0 + dd];
            }
#pragma unroll
            for (int c = 0; c < 4; ++c) {
                float wqv[10], wfv[10], wcv[10];
#pragma unroll
                for (int k = 0; k < 10; ++k) {
                    int idx = (dd + c) * LL1 + l0 + k;
                    wqv[k] = wq[idx];
                    wfv[k] = wf[idx];
                    wcv[k] = wc[idx];
                }
#pragma unroll
                for (int j = 0; j < 4; ++j) {
                    float qv = ((const float*)&q4[j])[c];
                    float fv = ((const float*)&f4[j])[c];
                    float qf = qv * fv;
#pragma unroll
                    for (int k = 0; k < 10; ++k)
                        acc[j * 10 + k] = fmaf(qv, wqv[k],
                                          fmaf(fv, wfv[k],
                                          fmaf(qf, wcv[k], acc[j * 10 + k])));
                }
            }
        }
    }

#pragma unroll
    for (int j = 0; j < 4; ++j)
#pragma unroll
        for (int k = 0; k < 10; ++k)
            z1[pr[j] * LL1 + l0 + k] = acc[j * 10 + k] + b1[l0 + k];
}

// ---------------------------------------------------------------------------
// DICE in-place: stats over s (dim 0, ddof=1) per column, then
// x -> x * (p + alpha*(1-p)),  p = sigmoid((x-mean)/std)
__global__ __launch_bounds__(256) void k_dice(
    float* __restrict__ z, int C, const float* __restrict__ alpha_p) {
    int col = blockIdx.x * 256 + threadIdx.x;
    if (col >= C) return;
    float sum = 0.f, sumsq = 0.f;
    for (int s = 0; s < SS; ++s) {
        float v = z[s * C + col];
        sum += v;
        sumsq = fmaf(v, v, sumsq);
    }
    float mean = sum * (1.f / SS);
    float var = (sumsq - (float)SS * mean * mean) * (1.f / (SS - 1));
    float istd = rsqrtf(var);
    float alpha = *alpha_p;
    for (int s = 0; s < SS; ++s) {
        float v = z[s * C + col];
        float p = 1.f / (1.f + expf(-(v - mean) * istd));
        z[s * C + col] = v * (p + alpha * (1.f - p));
    }
}

// ---------------------------------------------------------------------------
// K2: z2[m][n] = h1[m][:] @ W2 + b2.  M=204800, K=80, N=40.
__global__ __launch_bounds__(256) void k2_gemm2(
    const float* __restrict__ h1, const float* __restrict__ W2,
    const float* __restrict__ b2, float* __restrict__ z2) {
    const int tid = threadIdx.x;
    const int m0  = blockIdx.x * 128;
    __shared__ float lh[128 * LL1];
    __shared__ float lw[LL1 * LL2];
    for (int e = tid; e < 128 * LL1; e += 256) lh[e] = h1[m0 * LL1 + e];
    for (int e = tid; e < LL1 * LL2; e += 256) lw[e] = W2[e];
    __syncthreads();
    const int m  = tid & 127;
    const int n0 = (tid >> 7) * 20;
    float acc[20];
#pragma unroll
    for (int i = 0; i < 20; ++i) acc[i] = 0.f;
    for (int k = 0; k < LL1; ++k) {
        float hv = lh[m * LL1 + k];
#pragma unroll
        for (int n = 0; n < 20; ++n)
            acc[n] = fmaf(hv, lw[k * LL2 + n0 + n], acc[n]);
    }
#pragma unroll
    for (int n = 0; n < 20; ++n)
        z2[(m0 + m) * LL2 + n0 + n] = acc[n] + b2[n0 + n];
}

// ---------------------------------------------------------------------------
// K3: per batch b: logits[s] = h2[s][b][:]@W3 + b3, masked softmax over s,
// write normalized weights to wbuf[s*B + b].
__global__ __launch_bounds__(256) void k3_softmax(
    const float* __restrict__ h2, const float* __restrict__ W3,
    const float* __restrict__ b3, const void* __restrict__ mask,
    const int* __restrict__ flag, float* __restrict__ wbuf) {
    const int b   = blockIdx.x;
    const int tid = threadIdx.x;
    __shared__ float red[4];
    const int boolLayout = *flag;

    float logit = -3.0e38f;
    if (tid < SS) {
        const float* hrow = &h2[(tid * BB + b) * LL2];
        float dot = b3[0];
#pragma unroll
        for (int k = 0; k < LL2; ++k) dot = fmaf(hrow[k], W3[k], dot);
        int mi = tid * BB + b;
        bool m = boolLayout ? (((const unsigned char*)mask)[mi] != 0)
                            : (((const int*)mask)[mi] != 0);
        logit = m ? dot : MASK_FILL_F;
    }
    // block max
    float v = logit;
#pragma unroll
    for (int off = 1; off < 64; off <<= 1) v = fmaxf(v, __shfl_xor(v, off, 64));
    if ((tid & 63) == 0) red[tid >> 6] = v;
    __syncthreads();
    float smax = fmaxf(fmaxf(red[0], red[1]), fmaxf(red[2], red[3]));
    __syncthreads();           // protect red[] reuse
    float e = (tid < SS) ? expf(logit - smax) : 0.f;
    v = e;
#pragma unroll
    for (int off = 1; off < 64; off <<= 1) v += __shfl_xor(v, off, 64);
    if ((tid & 63) == 0) red[tid >> 6] = v;
    __syncthreads();
    float inv = 1.f / (red[0] + red[1] + red[2] + red[3]);
    if (tid < SS) wbuf[tid * BB + b] = e * inv;
}

// ---------------------------------------------------------------------------
// K4: out[s][b][d] = wbuf[s][b] * facts[s][b][d]   (float4 elementwise)
__global__ __launch_bounds__(256) void k4_scale(
    const float* __restrict__ wbuf, const float* __restrict__ facts,
    float* __restrict__ out) {
    int i = blockIdx.x * 256 + threadIdx.x;   // float4 index
    int row = (i * 4) >> 7;                   // (s*B + b)
    float w = wbuf[row];
    float4 f = ((const float4*)facts)[i];
    float4 o;
    o.x = f.x * w; o.y = f.y * w; o.z = f.z * w; o.w = f.w * w;
    ((float4*)out)[i] = o;
}

// ---------------------------------------------------------------------------
extern "C" void kernel_launch(void* const* d_in, const int* in_sizes, int n_in,
                              void* d_out, int out_size, void* d_ws, size_t ws_size,
                              hipStream_t stream) {
    const float* query = (const float*)d_in[0];
    const float* facts = (const float*)d_in[1];
    const void*  mask  = d_in[2];
    const float* W1 = (const float*)d_in[3];
    const float* b1 = (const float*)d_in[4];
    const float* a1 = (const float*)d_in[5];
    const float* W2 = (const float*)d_in[6];
    const float* b2 = (const float*)d_in[7];
    const float* a2 = (const float*)d_in[8];
    const float* W3 = (const float*)d_in[9];
    const float* b3 = (const float*)d_in[10];
    float* out = (float*)d_out;

    // d_out (26.2M floats) doubles as scratch:
    //   z1/h1: first 16.384M floats; z2/h2: next 8.192M floats.
    // Final output only written after z1 and z2 are dead (k3 consumes z2 into
    // wbuf before k4 writes out).
    float* z1 = out;
    float* z2 = out + (size_t)PP * LL1;       // 16,384,000 .. 24,576,000 < 26,214,400
    float* wbuf = (float*)d_ws;               // S*B floats = 819,200 B
    int*   flag = (int*)((char*)d_ws + (1u << 20));

    k_detect_mask<<<1, 1, 0, stream>>>((const unsigned char*)mask, flag);
    k1_gemm1<<<PP / 128, 256, 0, stream>>>(query, facts, W1, b1, z1);
    k_dice<<<(BB * LL1) / 256, 256, 0, stream>>>(z1, BB * LL1, a1);
    k2_gemm2<<<PP / 128, 256, 0, stream>>>(z1, W2, b2, z2);
    k_dice<<<(BB * LL2) / 256, 256, 0, stream>>>(z2, BB * LL2, a2);
    k3_softmax<<<BB, 256, 0, stream>>>(z2, W3, b3, mask, flag, wbuf);
    k4_scale<<<(PP * DD) / (256 * 4), 256, 0, stream>>>(wbuf, facts, out);
}

// Round 2
// 430.178 us; speedup vs baseline: 1.4005x; 1.4005x over previous
//
#include <hip/hip_runtime.h>
#include <hip/hip_bf16.h>
#include <math.h>

#define SS 200
#define BB 1024
#define DD 128
#define FF 512
#define LL1 80
#define LL2 40
#define PP (SS*BB)            // 204800 flattened (s,b) pairs
#define MASK_FILL_F (-4294967295.0f)

typedef short bf16x8 __attribute__((ext_vector_type(8)));
typedef float f32x4  __attribute__((ext_vector_type(4)));

static __device__ __forceinline__ unsigned short f2bf(float x) {
    __hip_bfloat16 h = __float2bfloat16(x);
    return *reinterpret_cast<unsigned short*>(&h);
}
static __device__ __forceinline__ float bf2f(unsigned short u) {
    __hip_bfloat16 h = *reinterpret_cast<__hip_bfloat16*>(&u);
    return __bfloat162float(h);
}

// ---------------------------------------------------------------------------
// K0: detect mask storage layout (int32 0/1 vs 1-byte bool).
__global__ void k_detect_mask(const unsigned char* __restrict__ mask, int* __restrict__ flag) {
    if (threadIdx.x == 0 && blockIdx.x == 0) {
        int f = 0;
        for (int i = 0; i < 256; ++i)
            if ((i & 3) && mask[i]) f = 1;
        *flag = f;
    }
}

// ---------------------------------------------------------------------------
// Prep: fold W1 into 3 segments (Wq=Wa+Wd, Wf=Wb-Wd, Wc), split hi/lo bf16,
// and store pre-swizzled MFMA B-fragments:
//   bfr[(((seg*2+hl)*4 + kt)*5 + nt)*64 + lane][8]
// B[k][n]: n = nt*16 + (lane&15), k = kt*32 + (lane>>4)*8 + j.
__global__ void k_prep_w1(const float* __restrict__ W1, unsigned short* __restrict__ bfr) {
    int t = blockIdx.x * 256 + threadIdx.x;
    if (t >= 120 * 64) return;
    int lane = t & 63;
    int fid  = t >> 6;
    int nt   = fid % 5;
    int kt   = (fid / 5) & 3;
    int hl   = (fid / 20) & 1;
    int seg  = fid / 40;
    int n     = nt * 16 + (lane & 15);
    int kbase = kt * 32 + (lane >> 4) * 8;
    unsigned short* o = bfr + (size_t)t * 8;
#pragma unroll
    for (int j = 0; j < 8; ++j) {
        int k = kbase + j;
        float w;
        if (seg == 0)      w = W1[k * LL1 + n] + W1[(384 + k) * LL1 + n];
        else if (seg == 1) w = W1[(128 + k) * LL1 + n] - W1[(384 + k) * LL1 + n];
        else               w = W1[(256 + k) * LL1 + n];
        unsigned short hb = f2bf(w);
        o[j] = (hl == 0) ? hb : f2bf(w - bf2f(hb));
    }
}

// ---------------------------------------------------------------------------
// K1: z1[p][l] = q·Wq + f·Wf + (q*f)·Wc + b1 via split-bf16 MFMA 16x16x32.
// Wave handles 16 rows x 80 cols. Block = 4 waves = 64 rows. No LDS.
__global__ __launch_bounds__(256) void k1_mfma(
    const float* __restrict__ query, const float* __restrict__ facts,
    const unsigned short* __restrict__ bfr, const float* __restrict__ b1,
    float* __restrict__ z1) {
    const int tid  = threadIdx.x;
    const int lane = tid & 63;
    const int wave = tid >> 6;
    const int p0   = blockIdx.x * 64 + wave * 16;
    const int m    = lane & 15;
    const int quad = lane >> 4;
    const int p    = p0 + m;
    const int qp   = p / SS;           // tile+reshape permutation: q row = p/S

    f32x4 acc[5];
#pragma unroll
    for (int i = 0; i < 5; ++i) acc[i] = (f32x4){0.f, 0.f, 0.f, 0.f};

    const float* fRow = facts + (size_t)p * DD;
    const float* qRow = query + (size_t)qp * DD;

    for (int kt = 0; kt < 4; ++kt) {
        const int dbase = kt * 32 + quad * 8;
        float q8[8], f8[8];
        *(float4*)&q8[0] = *(const float4*)(qRow + dbase);
        *(float4*)&q8[4] = *(const float4*)(qRow + dbase + 4);
        *(float4*)&f8[0] = *(const float4*)(fRow + dbase);
        *(float4*)&f8[4] = *(const float4*)(fRow + dbase + 4);

#pragma unroll
        for (int seg = 0; seg < 3; ++seg) {
            bf16x8 ah, al;
#pragma unroll
            for (int j = 0; j < 8; ++j) {
                float x = (seg == 0) ? q8[j] : (seg == 1 ? f8[j] : q8[j] * f8[j]);
                unsigned short hb = f2bf(x);
                ah[j] = (short)hb;
                al[j] = (short)f2bf(x - bf2f(hb));
            }
            const unsigned short* bh0 = bfr + ((((size_t)(seg * 2 + 0) * 4 + kt) * 5) * 64 + lane) * 8;
            const unsigned short* bl0 = bfr + ((((size_t)(seg * 2 + 1) * 4 + kt) * 5) * 64 + lane) * 8;
#pragma unroll
            for (int nt = 0; nt < 5; ++nt) {
                bf16x8 Bh = *(const bf16x8*)(bh0 + (size_t)nt * 64 * 8);
                bf16x8 Bl = *(const bf16x8*)(bl0 + (size_t)nt * 64 * 8);
                acc[nt] = __builtin_amdgcn_mfma_f32_16x16x32_bf16(ah, Bh, acc[nt], 0, 0, 0);
                acc[nt] = __builtin_amdgcn_mfma_f32_16x16x32_bf16(al, Bh, acc[nt], 0, 0, 0);
                acc[nt] = __builtin_amdgcn_mfma_f32_16x16x32_bf16(ah, Bl, acc[nt], 0, 0, 0);
            }
        }
    }
    // C/D layout: col = lane&15, row = quad*4 + reg
#pragma unroll
    for (int nt = 0; nt < 5; ++nt) {
        int n = nt * 16 + m;
        float bias = b1[n];
#pragma unroll
        for (int r = 0; r < 4; ++r) {
            int row = quad * 4 + r;
            z1[(size_t)(p0 + row) * LL1 + n] = acc[nt][r] + bias;
        }
    }
}

// ---------------------------------------------------------------------------
// Stats: per-(b,l) column sum/sumsq over s via atomics. grid (C/256, 8).
__global__ __launch_bounds__(256) void k_stats(
    const float* __restrict__ z, int C,
    float* __restrict__ sum, float* __restrict__ sumsq) {
    int col = blockIdx.x * 256 + threadIdx.x;
    int s0  = blockIdx.y * 25;
    const float* pz = z + (size_t)s0 * C + col;
    float ps = 0.f, pss = 0.f;
#pragma unroll 5
    for (int i = 0; i < 25; ++i) {
        float v = pz[(size_t)i * C];
        ps += v;
        pss = fmaf(v, v, pss);
    }
    atomicAdd(&sum[col], ps);
    atomicAdd(&sumsq[col], pss);
}

// ---------------------------------------------------------------------------
// K2: dice1-on-load + GEMM (K=80, N=40). Block: 128 rows, 256 threads.
__global__ __launch_bounds__(256) void k2_fused(
    const float* __restrict__ h1raw, const float* __restrict__ sum1,
    const float* __restrict__ sumsq1, const float* __restrict__ a1,
    const float* __restrict__ W2, const float* __restrict__ b2,
    float* __restrict__ z2) {
    const int tid = threadIdx.x;
    const int m0  = blockIdx.x * 128;
    __shared__ float lh[128 * LL1];
    __shared__ float lw[LL1 * LL2];
    const float alpha = *a1;
    for (int e = tid; e < 128 * LL1; e += 256) {
        int r = e / LL1, l = e - r * LL1;
        int b = (m0 + r) & (BB - 1);
        int col = b * LL1 + l;
        float v    = h1raw[(size_t)m0 * LL1 + e];
        float mean = sum1[col] * (1.f / SS);
        float var  = (sumsq1[col] - (float)SS * mean * mean) * (1.f / (SS - 1));
        float istd = rsqrtf(var);
        float pp   = 1.f / (1.f + expf(-(v - mean) * istd));
        lh[e] = v * (pp + alpha * (1.f - pp));
    }
    for (int e = tid; e < LL1 * LL2; e += 256) lw[e] = W2[e];
    __syncthreads();
    const int m  = tid & 127;
    const int n0 = (tid >> 7) * 20;
    float acc[20];
#pragma unroll
    for (int i = 0; i < 20; ++i) acc[i] = 0.f;
    for (int k = 0; k < LL1; ++k) {
        float hv = lh[m * LL1 + k];
#pragma unroll
        for (int n = 0; n < 20; ++n)
            acc[n] = fmaf(hv, lw[k * LL2 + n0 + n], acc[n]);
    }
#pragma unroll
    for (int n = 0; n < 20; ++n)
        z2[(size_t)(m0 + m) * LL2 + n0 + n] = acc[n] + b2[n0 + n];
}

// ---------------------------------------------------------------------------
// K3: dice2 inline + W3 dot + masked softmax over s. One block per b.
__global__ __launch_bounds__(256) void k3_fused(
    const float* __restrict__ z2raw, const float* __restrict__ sum2,
    const float* __restrict__ sumsq2, const float* __restrict__ a2,
    const float* __restrict__ W3, const float* __restrict__ b3,
    const void* __restrict__ mask, const int* __restrict__ flag,
    float* __restrict__ wbuf) {
    const int b   = blockIdx.x;
    const int tid = threadIdx.x;
    __shared__ float smean[LL2], sistd[LL2], sw3[LL2];
    __shared__ float red[4];
    if (tid < LL2) {
        int col = b * LL2 + tid;
        float mean = sum2[col] * (1.f / SS);
        float var  = (sumsq2[col] - (float)SS * mean * mean) * (1.f / (SS - 1));
        smean[tid] = mean;
        sistd[tid] = rsqrtf(var);
        sw3[tid]   = W3[tid];
    }
    __syncthreads();
    const float alpha = *a2;
    const int boolLayout = *flag;

    float logit = -3.0e38f;
    float e = 0.f;
    if (tid < SS) {
        const float* row = z2raw + (size_t)(tid * BB + b) * LL2;
        float dot = b3[0];
#pragma unroll
        for (int k = 0; k < LL2; ++k) {
            float v  = row[k];
            float pp = 1.f / (1.f + expf(-(v - smean[k]) * sistd[k]));
            float h  = v * (pp + alpha * (1.f - pp));
            dot = fmaf(h, sw3[k], dot);
        }
        int mi = tid * BB + b;
        bool mk = boolLayout ? (((const unsigned char*)mask)[mi] != 0)
                             : (((const int*)mask)[mi] != 0);
        logit = mk ? dot : MASK_FILL_F;
    }
    float v = logit;
#pragma unroll
    for (int off = 1; off < 64; off <<= 1) v = fmaxf(v, __shfl_xor(v, off, 64));
    if ((tid & 63) == 0) red[tid >> 6] = v;
    __syncthreads();
    float smax = fmaxf(fmaxf(red[0], red[1]), fmaxf(red[2], red[3]));
    __syncthreads();
    e = (tid < SS) ? expf(logit - smax) : 0.f;
    v = e;
#pragma unroll
    for (int off = 1; off < 64; off <<= 1) v += __shfl_xor(v, off, 64);
    if ((tid & 63) == 0) red[tid >> 6] = v;
    __syncthreads();
    float inv = 1.f / (red[0] + red[1] + red[2] + red[3]);
    if (tid < SS) wbuf[tid * BB + b] = e * inv;
}

// ---------------------------------------------------------------------------
// K4: out[s][b][d] = wbuf[s][b] * facts[s][b][d]
__global__ __launch_bounds__(256) void k4_scale(
    const float* __restrict__ wbuf, const float* __restrict__ facts,
    float* __restrict__ out) {
    int i = blockIdx.x * 256 + threadIdx.x;
    int row = (i * 4) >> 7;
    float w = wbuf[row];
    float4 f = ((const float4*)facts)[i];
    float4 o;
    o.x = f.x * w; o.y = f.y * w; o.z = f.z * w; o.w = f.w * w;
    ((float4*)out)[i] = o;
}

// ---------------------------------------------------------------------------
extern "C" void kernel_launch(void* const* d_in, const int* in_sizes, int n_in,
                              void* d_out, int out_size, void* d_ws, size_t ws_size,
                              hipStream_t stream) {
    const float* query = (const float*)d_in[0];
    const float* facts = (const float*)d_in[1];
    const void*  mask  = d_in[2];
    const float* W1 = (const float*)d_in[3];
    const float* b1 = (const float*)d_in[4];
    const float* a1 = (const float*)d_in[5];
    const float* W2 = (const float*)d_in[6];
    const float* b2 = (const float*)d_in[7];
    const float* a2 = (const float*)d_in[8];
    const float* W3 = (const float*)d_in[9];
    const float* b3 = (const float*)d_in[10];
    float* out = (float*)d_out;

    // d_out scratch layout: z1 [0,16.384M) ; z2 [16.384M,24.576M) ;
    // stats in the slack [24.576M, 26.214M) — dead before k4 overwrites out.
    float* z1 = out;
    float* z2 = out + (size_t)PP * LL1;
    float* sbase  = out + (size_t)PP * (LL1 + LL2);   // 24,576,000
    float* sum1   = sbase;                // 81920
    float* sumsq1 = sbase + 81920;        // 81920
    float* sum2   = sbase + 163840;       // 40960
    float* sumsq2 = sbase + 204800;       // 40960 -> ends 245760 floats
    // ws layout: B-frags [0,122880) ; wbuf @128K ; flag @1M (as round 1)
    unsigned short* bfr = (unsigned short*)d_ws;
    float* wbuf = (float*)((char*)d_ws + 131072);
    int*   flag = (int*)((char*)d_ws + (1u << 20));

    k_detect_mask<<<1, 1, 0, stream>>>((const unsigned char*)mask, flag);
    k_prep_w1<<<30, 256, 0, stream>>>(W1, bfr);
    hipMemsetAsync(sbase, 0, 245760 * sizeof(float), stream);
    k1_mfma<<<PP / 64, 256, 0, stream>>>(query, facts, bfr, b1, z1);
    k_stats<<<dim3((BB * LL1) / 256, 8), 256, 0, stream>>>(z1, BB * LL1, sum1, sumsq1);
    k2_fused<<<PP / 128, 256, 0, stream>>>(z1, sum1, sumsq1, a1, W2, b2, z2);
    k_stats<<<dim3((BB * LL2) / 256, 8), 256, 0, stream>>>(z2, BB * LL2, sum2, sumsq2);
    k3_fused<<<BB, 256, 0, stream>>>(z2, sum2, sumsq2, a2, W3, b3, mask, flag, wbuf);
    k4_scale<<<(PP * DD) / (256 * 4), 256, 0, stream>>>(wbuf, facts, out);
}

// Round 3
// 352.757 us; speedup vs baseline: 1.7079x; 1.2195x over previous
//
#include <hip/hip_runtime.h>
#include <hip/hip_bf16.h>
#include <math.h>

#define SS 200
#define BB 1024
#define DD 128
#define FF 512
#define LL1 80
#define LL2 40
#define PP (SS*BB)            // 204800 flattened (s,b) pairs
#define MASK_FILL_F (-4294967295.0f)

typedef short bf16x8 __attribute__((ext_vector_type(8)));
typedef float f32x4  __attribute__((ext_vector_type(4)));

static __device__ __forceinline__ unsigned short f2bf(float x) {
    __hip_bfloat16 h = __float2bfloat16(x);
    return *reinterpret_cast<unsigned short*>(&h);
}
static __device__ __forceinline__ float bf2f(unsigned short u) {
    __hip_bfloat16 h = *reinterpret_cast<__hip_bfloat16*>(&u);
    return __bfloat162float(h);
}
// truncation split: hi = top 16 bits, lo = bf16(x - hi). |err| ~ 2^-16 rel.
static __device__ __forceinline__ void split8(const float* x, bf16x8& ah, bf16x8& al) {
#pragma unroll
    for (int j = 0; j < 8; ++j) {
        unsigned u = __float_as_uint(x[j]);
        ah[j] = (short)(u >> 16);
        float hi = __uint_as_float(u & 0xffff0000u);
        al[j] = (short)f2bf(x[j] - hi);
    }
}

// ---------------------------------------------------------------------------
// K0: detect mask storage layout (int32 0/1 vs 1-byte bool).
__global__ void k_detect_mask(const unsigned char* __restrict__ mask, int* __restrict__ flag) {
    if (threadIdx.x == 0 && blockIdx.x == 0) {
        int f = 0;
        for (int i = 0; i < 256; ++i)
            if ((i & 3) && mask[i]) f = 1;
        *flag = f;
    }
}

// ---------------------------------------------------------------------------
// Prep W1: fold into 3 segments (Wq=Wa+Wd, Wf=Wb-Wd, Wc), split hi/lo bf16,
// pre-swizzled MFMA B-fragments: bfr[(((seg*2+hl)*4 + kt)*5 + nt)*64 + lane][8]
// B[k][n]: n = nt*16 + (lane&15), k = kt*32 + (lane>>4)*8 + j.
__global__ void k_prep_w1(const float* __restrict__ W1, unsigned short* __restrict__ bfr) {
    int t = blockIdx.x * 256 + threadIdx.x;
    if (t >= 120 * 64) return;
    int lane = t & 63;
    int fid  = t >> 6;
    int nt   = fid % 5;
    int kt   = (fid / 5) & 3;
    int hl   = (fid / 20) & 1;
    int seg  = fid / 40;
    int n     = nt * 16 + (lane & 15);
    int kbase = kt * 32 + (lane >> 4) * 8;
    unsigned short* o = bfr + (size_t)t * 8;
#pragma unroll
    for (int j = 0; j < 8; ++j) {
        int k = kbase + j;
        float w;
        if (seg == 0)      w = W1[k * LL1 + n] + W1[(384 + k) * LL1 + n];
        else if (seg == 1) w = W1[(128 + k) * LL1 + n] - W1[(384 + k) * LL1 + n];
        else               w = W1[(256 + k) * LL1 + n];
        unsigned short hb = f2bf(w);
        o[j] = (hl == 0) ? hb : f2bf(w - bf2f(hb));
    }
}

// ---------------------------------------------------------------------------
// Prep W2: pad K 80->96, N 40->48; frag id (kt*3+nt)*2+hl, 18 frags (18 KB).
__global__ void k_prep_w2(const float* __restrict__ W2, unsigned short* __restrict__ bfr2) {
    int t = blockIdx.x * 256 + threadIdx.x;
    if (t >= 18 * 64) return;
    int lane = t & 63;
    int fid  = t >> 6;
    int hl   = fid & 1;
    int nt   = (fid >> 1) % 3;
    int kt   = fid / 6;
    int n  = nt * 16 + (lane & 15);
    int kb = kt * 32 + (lane >> 4) * 8;
    unsigned short* o = bfr2 + (size_t)t * 8;
#pragma unroll
    for (int j = 0; j < 8; ++j) {
        int k = kb + j;
        float w = (k < LL1 && n < LL2) ? W2[k * LL2 + n] : 0.f;
        unsigned short hb = f2bf(w);
        o[j] = (hl == 0) ? hb : f2bf(w - bf2f(hb));
    }
}

// ---------------------------------------------------------------------------
// K1: z1[p][l] = q·Wq + f·Wf + (q*f)·Wc + b1 via split-bf16 MFMA 16x16x32.
// Wave = 64 rows (4 row-tiles of 16): B-frags per (kt,seg) feed 4 tiles.
__global__ __launch_bounds__(256, 2) void k1_mfma(
    const float* __restrict__ query, const float* __restrict__ facts,
    const unsigned short* __restrict__ bfr, const float* __restrict__ b1,
    float* __restrict__ z1) {
    const int tid  = threadIdx.x;
    const int lane = tid & 63;
    const int m    = lane & 15;
    const int quad = lane >> 4;
    const int pw   = blockIdx.x * 256 + (tid >> 6) * 64;

    f32x4 acc[4][5];
#pragma unroll
    for (int t = 0; t < 4; ++t)
#pragma unroll
        for (int nt = 0; nt < 5; ++nt) acc[t][nt] = (f32x4){0.f, 0.f, 0.f, 0.f};

    int pr[4], qr[4];
#pragma unroll
    for (int t = 0; t < 4; ++t) {
        pr[t] = pw + t * 16 + m;
        qr[t] = pr[t] / SS;
    }

#pragma unroll 1
    for (int kt = 0; kt < 4; ++kt) {
        const int dbase = kt * 32 + quad * 8;
        float q8[4][8], f8[4][8];
#pragma unroll
        for (int t = 0; t < 4; ++t) {
            *(float4*)&q8[t][0] = *(const float4*)(query + (size_t)qr[t] * DD + dbase);
            *(float4*)&q8[t][4] = *(const float4*)(query + (size_t)qr[t] * DD + dbase + 4);
            *(float4*)&f8[t][0] = *(const float4*)(facts + (size_t)pr[t] * DD + dbase);
            *(float4*)&f8[t][4] = *(const float4*)(facts + (size_t)pr[t] * DD + dbase + 4);
        }
#pragma unroll
        for (int seg = 0; seg < 3; ++seg) {
            bf16x8 Bh[5], Bl[5];
            const unsigned short* bh0 = bfr + ((((size_t)(seg * 2 + 0) * 4 + kt) * 5) * 64 + lane) * 8;
            const unsigned short* bl0 = bfr + ((((size_t)(seg * 2 + 1) * 4 + kt) * 5) * 64 + lane) * 8;
#pragma unroll
            for (int nt = 0; nt < 5; ++nt) {
                Bh[nt] = *(const bf16x8*)(bh0 + (size_t)nt * 512);
                Bl[nt] = *(const bf16x8*)(bl0 + (size_t)nt * 512);
            }
#pragma unroll
            for (int t = 0; t < 4; ++t) {
                float x8[8];
#pragma unroll
                for (int j = 0; j < 8; ++j)
                    x8[j] = (seg == 0) ? q8[t][j] : (seg == 1 ? f8[t][j] : q8[t][j] * f8[t][j]);
                bf16x8 ah, al;
                split8(x8, ah, al);
#pragma unroll
                for (int nt = 0; nt < 5; ++nt) {
                    acc[t][nt] = __builtin_amdgcn_mfma_f32_16x16x32_bf16(ah, Bh[nt], acc[t][nt], 0, 0, 0);
                    acc[t][nt] = __builtin_amdgcn_mfma_f32_16x16x32_bf16(al, Bh[nt], acc[t][nt], 0, 0, 0);
                    acc[t][nt] = __builtin_amdgcn_mfma_f32_16x16x32_bf16(ah, Bl[nt], acc[t][nt], 0, 0, 0);
                }
            }
        }
    }
    // C/D layout: col = lane&15, row = quad*4 + reg
#pragma unroll
    for (int t = 0; t < 4; ++t)
#pragma unroll
        for (int nt = 0; nt < 5; ++nt) {
            int n = nt * 16 + m;
            float bias = b1[n];
#pragma unroll
            for (int r = 0; r < 4; ++r)
                z1[(size_t)(pw + t * 16 + quad * 4 + r) * LL1 + n] = acc[t][nt][r] + bias;
        }
}

// ---------------------------------------------------------------------------
// Stats for z1: per-(b,l) column sum/sumsq over s via atomics. grid (320, 8).
__global__ __launch_bounds__(256) void k_stats(
    const float* __restrict__ z, int C,
    float* __restrict__ sum, float* __restrict__ sumsq) {
    int col = blockIdx.x * 256 + threadIdx.x;
    int s0  = blockIdx.y * 25;
    const float* pz = z + (size_t)s0 * C + col;
    float ps = 0.f, pss = 0.f;
#pragma unroll 5
    for (int i = 0; i < 25; ++i) {
        float v = pz[(size_t)i * C];
        ps += v;
        pss = fmaf(v, v, pss);
    }
    atomicAdd(&sum[col], ps);
    atomicAdd(&sumsq[col], pss);
}

// ---------------------------------------------------------------------------
// K2: dice1-on-load + split-bf16 MFMA GEMM (K 80->96, N 40->48).
// Wave = 64 rows (4 tiles); all 18 W2 frags cached in registers.
// Output written TRANSPOSED: z2T[b][s][l].
__global__ __launch_bounds__(256, 2) void k2_mfma(
    const float* __restrict__ z1, const float* __restrict__ sum1,
    const float* __restrict__ sumsq1, const float* __restrict__ a1,
    const unsigned short* __restrict__ bfr2, const float* __restrict__ b2,
    float* __restrict__ z2T) {
    const int tid  = threadIdx.x;
    const int lane = tid & 63;
    const int m    = lane & 15;
    const int quad = lane >> 4;
    const int pw   = blockIdx.x * 256 + (tid >> 6) * 64;
    const float alpha = *a1;

    bf16x8 Bh[3][3], Bl[3][3];
#pragma unroll
    for (int kt = 0; kt < 3; ++kt)
#pragma unroll
        for (int nt = 0; nt < 3; ++nt) {
            Bh[kt][nt] = *(const bf16x8*)(bfr2 + (((size_t)(kt * 3 + nt) * 2 + 0) * 64 + lane) * 8);
            Bl[kt][nt] = *(const bf16x8*)(bfr2 + (((size_t)(kt * 3 + nt) * 2 + 1) * 64 + lane) * 8);
        }
    float b2v[3];
#pragma unroll
    for (int nt = 0; nt < 3; ++nt) {
        int n = nt * 16 + m;
        b2v[nt] = (n < LL2) ? b2[n] : 0.f;
    }

#pragma unroll 1
    for (int t = 0; t < 4; ++t) {
        const int p = pw + t * 16 + m;
        const int b = p & (BB - 1);
        f32x4 acc[3];
#pragma unroll
        for (int nt = 0; nt < 3; ++nt) acc[nt] = (f32x4){0.f, 0.f, 0.f, 0.f};

#pragma unroll
        for (int kt = 0; kt < 3; ++kt) {
            float x8[8];
            const int kb = kt * 32 + quad * 8;
            if (kt < 2 || quad < 2) {
                const float* zr = z1    + (size_t)p * LL1 + kb;
                const float* su = sum1  + (size_t)b * LL1 + kb;
                const float* sq = sumsq1 + (size_t)b * LL1 + kb;
                float vv[8], sv[8], qv[8];
                *(float4*)&vv[0] = *(const float4*)zr;
                *(float4*)&vv[4] = *(const float4*)(zr + 4);
                *(float4*)&sv[0] = *(const float4*)su;
                *(float4*)&sv[4] = *(const float4*)(su + 4);
                *(float4*)&qv[0] = *(const float4*)sq;
                *(float4*)&qv[4] = *(const float4*)(sq + 4);
#pragma unroll
                for (int j = 0; j < 8; ++j) {
                    float mean = sv[j] * (1.f / SS);
                    float var  = (qv[j] - (float)SS * mean * mean) * (1.f / (SS - 1));
                    float istd = rsqrtf(var);
                    float pp   = 1.f / (1.f + expf(-(vv[j] - mean) * istd));
                    x8[j] = vv[j] * (pp + alpha * (1.f - pp));
                }
            } else {
#pragma unroll
                for (int j = 0; j < 8; ++j) x8[j] = 0.f;
            }
            bf16x8 ah, al;
            split8(x8, ah, al);
#pragma unroll
            for (int nt = 0; nt < 3; ++nt) {
                acc[nt] = __builtin_amdgcn_mfma_f32_16x16x32_bf16(ah, Bh[kt][nt], acc[nt], 0, 0, 0);
                acc[nt] = __builtin_amdgcn_mfma_f32_16x16x32_bf16(al, Bh[kt][nt], acc[nt], 0, 0, 0);
                acc[nt] = __builtin_amdgcn_mfma_f32_16x16x32_bf16(ah, Bl[kt][nt], acc[nt], 0, 0, 0);
            }
        }
        // epilogue: row = quad*4+r, col n = nt*16 + m (skip n>=40)
#pragma unroll
        for (int r = 0; r < 4; ++r) {
            const int prow = pw + t * 16 + quad * 4 + r;
            const int br = prow & (BB - 1);
            const int sr = prow >> 10;
            float* o = z2T + (size_t)br * (SS * LL2) + (size_t)sr * LL2;
#pragma unroll
            for (int nt = 0; nt < 3; ++nt) {
                int n = nt * 16 + m;
                if (n < LL2) o[n] = acc[nt][r] + b2v[nt];
            }
        }
    }
}

// ---------------------------------------------------------------------------
// K3: per b: stage z2T[b] (200x40) to LDS, in-block stats over s, dice2,
// W3 dot, masked softmax over s -> wbufT[b][s].
__global__ __launch_bounds__(256) void k3_fused(
    const float* __restrict__ z2T, const float* __restrict__ a2,
    const float* __restrict__ W3, const float* __restrict__ b3,
    const void* __restrict__ mask, const int* __restrict__ flag,
    float* __restrict__ wbufT) {
    const int b   = blockIdx.x;
    const int tid = threadIdx.x;
    __shared__ float lds[SS * 41];       // stride 41: conflict-free both phases
    __shared__ float smean[LL2], sistd[LL2], sw3[LL2];
    __shared__ float red[4];

    const float4* src = (const float4*)(z2T + (size_t)b * (SS * LL2));
    for (int i = tid; i < (SS * LL2) / 4; i += 256) {
        float4 v = src[i];
        int s = i / 10;
        int o = (i - s * 10) * 4;
        float* d = &lds[s * 41 + o];
        d[0] = v.x; d[1] = v.y; d[2] = v.z; d[3] = v.w;
    }
    __syncthreads();
    if (tid < LL2) {
        float sum = 0.f, ssq = 0.f;
        for (int s = 0; s < SS; ++s) {
            float v = lds[s * 41 + tid];
            sum += v;
            ssq = fmaf(v, v, ssq);
        }
        float mean = sum * (1.f / SS);
        float var  = (ssq - (float)SS * mean * mean) * (1.f / (SS - 1));
        smean[tid] = mean;
        sistd[tid] = rsqrtf(var);
        sw3[tid]   = W3[tid];
    }
    __syncthreads();
    const float alpha = *a2;
    const int boolLayout = *flag;

    float logit = -3.0e38f;
    if (tid < SS) {
        float dot = b3[0];
#pragma unroll
        for (int k = 0; k < LL2; ++k) {
            float v  = lds[tid * 41 + k];
            float pp = 1.f / (1.f + expf(-(v - smean[k]) * sistd[k]));
            float h  = v * (pp + alpha * (1.f - pp));
            dot = fmaf(h, sw3[k], dot);
        }
        int mi = tid * BB + b;
        bool mk = boolLayout ? (((const unsigned char*)mask)[mi] != 0)
                             : (((const int*)mask)[mi] != 0);
        logit = mk ? dot : MASK_FILL_F;
    }
    float v = logit;
#pragma unroll
    for (int off = 1; off < 64; off <<= 1) v = fmaxf(v, __shfl_xor(v, off, 64));
    if ((tid & 63) == 0) red[tid >> 6] = v;
    __syncthreads();
    float smax = fmaxf(fmaxf(red[0], red[1]), fmaxf(red[2], red[3]));
    __syncthreads();
    float e = (tid < SS) ? expf(logit - smax) : 0.f;
    v = e;
#pragma unroll
    for (int off = 1; off < 64; off <<= 1) v += __shfl_xor(v, off, 64);
    if ((tid & 63) == 0) red[tid >> 6] = v;
    __syncthreads();
    float inv = 1.f / (red[0] + red[1] + red[2] + red[3]);
    if (tid < SS) wbufT[(size_t)b * SS + tid] = e * inv;
}

// ---------------------------------------------------------------------------
// K4: out[s][b][d] = wbufT[b][s] * facts[s][b][d]
__global__ __launch_bounds__(256) void k4_scale(
    const float* __restrict__ wbufT, const float* __restrict__ facts,
    float* __restrict__ out) {
    int i = blockIdx.x * 256 + threadIdx.x;   // float4 index
    int p = i >> 5;                           // (s*B + b), 32 float4 per row
    float w = wbufT[(size_t)(p & (BB - 1)) * SS + (p >> 10)];
    float4 f = ((const float4*)facts)[i];
    float4 o;
    o.x = f.x * w; o.y = f.y * w; o.z = f.z * w; o.w = f.w * w;
    ((float4*)out)[i] = o;
}

// ---------------------------------------------------------------------------
extern "C" void kernel_launch(void* const* d_in, const int* in_sizes, int n_in,
                              void* d_out, int out_size, void* d_ws, size_t ws_size,
                              hipStream_t stream) {
    const float* query = (const float*)d_in[0];
    const float* facts = (const float*)d_in[1];
    const void*  mask  = d_in[2];
    const float* W1 = (const float*)d_in[3];
    const float* b1 = (const float*)d_in[4];
    const float* a1 = (const float*)d_in[5];
    const float* W2 = (const float*)d_in[6];
    const float* b2 = (const float*)d_in[7];
    const float* a2 = (const float*)d_in[8];
    const float* W3 = (const float*)d_in[9];
    const float* b3 = (const float*)d_in[10];
    float* out = (float*)d_out;

    // d_out scratch (26,214,400 floats total; all dead before k4 overwrites):
    //   z1   [0, 16,384,000)
    //   z2T  [16,384,000, 24,576,000)          (layout [b][s][l])
    //   sum1 [24,576,000, +81,920) ; sumsq1 [+81,920)
    //   bfr1 @ float 24,739,840 (122,880 shorts) ; bfr2 @ 24,801,280 (9,216 shorts)
    float* z1  = out;
    float* z2T = out + (size_t)PP * LL1;
    float* sum1   = out + 24576000;
    float* sumsq1 = out + 24657920;
    unsigned short* bfr1 = (unsigned short*)(out + 24739840);
    unsigned short* bfr2 = (unsigned short*)(out + 24801280);
    // ws: wbufT (819,200 B) @0 ; flag @ 900 KiB. (ws >= 1 MiB proven in R1/R2.)
    float* wbufT = (float*)d_ws;
    int*   flag  = (int*)((char*)d_ws + 900 * 1024);

    k_detect_mask<<<1, 1, 0, stream>>>((const unsigned char*)mask, flag);
    k_prep_w1<<<30, 256, 0, stream>>>(W1, bfr1);
    k_prep_w2<<<5, 256, 0, stream>>>(W2, bfr2);
    hipMemsetAsync(sum1, 0, 163840 * sizeof(float), stream);
    k1_mfma<<<PP / 256, 256, 0, stream>>>(query, facts, bfr1, b1, z1);
    k_stats<<<dim3((BB * LL1) / 256, 8), 256, 0, stream>>>(z1, BB * LL1, sum1, sumsq1);
    k2_mfma<<<PP / 256, 256, 0, stream>>>(z1, sum1, sumsq1, a1, bfr2, b2, z2T);
    k3_fused<<<BB, 256, 0, stream>>>(z2T, a2, W3, b3, mask, flag, wbufT);
    k4_scale<<<(PP * DD) / (256 * 4), 256, 0, stream>>>(wbufT, facts, out);
}